// Round 10
// baseline (175.637 us; speedup 1.0000x reference)
//
#include <hip/hip_runtime.h>
#include <math.h>

#define T_SEQ 4096
#define NBATCH 4
#define NEMBD 1024
#define HS 64
#define BT (NBATCH * T_SEQ)   // 16384

typedef float f32x4 __attribute__((ext_vector_type(4)));
typedef short s8v  __attribute__((ext_vector_type(8)));   // 8 x bf16 bits
typedef short s4v  __attribute__((ext_vector_type(4)));   // 4 x bf16 bits

__device__ __forceinline__ short f2b_rne(float f) {
    union { float f; unsigned u; } v; v.f = f;
    unsigned r = v.u + 0x7fffu + ((v.u >> 16) & 1u);
    return (short)(r >> 16);
}
// pack 2 fp32 -> 2 bf16 (truncate) in one v_perm
__device__ __forceinline__ unsigned pk2(float lo, float hi) {
    return __builtin_amdgcn_perm(__float_as_uint(hi), __float_as_uint(lo), 0x07060302u);
}

// ---------------------------------------------------------------------------
// Kernel 1: W{q,k,v} [1024x64] fp32 -> Wt[192][1024] bf16 transposed.
// Softmax scale C^-0.5 * log2(e) folded into Wq.
// ---------------------------------------------------------------------------
__global__ __launch_bounds__(256) void wtrans_kernel(
        const float* __restrict__ Wq, const float* __restrict__ Wk,
        const float* __restrict__ Wv, short* __restrict__ Wt) {
    int e = blockIdx.x * 256 + threadIdx.x;
    int col = e & 63, k = (e >> 6) & 1023, mat = e >> 16;
    const float* W = (mat == 0) ? Wq : ((mat == 1) ? Wk : Wv);
    float scale = (mat == 0) ? 0.0450842298f : 1.0f;   // 2^-5 * log2(e)
    Wt[(size_t)(mat * 64 + col) * 1024 + k] = f2b_rne(W[k * 64 + col] * scale);
}

// ---------------------------------------------------------------------------
// Kernel 2: projections — R20 rewrite.
// R19's proj staged BOTH x and W through LDS with 2 barriers per 64-k step;
// ~22us vs a ~12us roofline (x read 67MB + 6.4 GFLOP MFMA).  The W staging
// was pure overhead: W b-frags touch the same 16 cache lines per b128
// whether read from LDS or L2 (quad offsets tile the lines), and Wt (384KB
// bf16) is L2-resident.  R20:
//  * W b-frags read DIRECTLY from Wt, double-buffered in registers one step
//    ahead (bA/bB, compile-time indexed) so L2 latency hides under MFMAs.
//    Live set ~84 VGPR < the 512-thread-proven 128 cap.
//  * x stays LDS-staged (genuine 16-row cross-lane reuse) but double-
//    buffered (xs[2]) -> ONE barrier per step instead of two.
//  * identical math: same pk2 truncation, same MFMA order, same epilogue.
// ---------------------------------------------------------------------------
__global__ __launch_bounds__(512) void proj_kernel(
        const float* __restrict__ xf, const short* __restrict__ Wt,
        short* __restrict__ QKV) {
    __shared__ short xs[2][32 * 72];
    int tid = threadIdx.x;
    int w = tid >> 6, l = tid & 63, quad = l >> 4, c16 = l & 15;
    int rt = w >> 2, cg = w & 3;
    int row0 = blockIdx.x * 32;
    short* VpT = QKV + 2 * (size_t)BT * HS;   // tiled [b][kt][64 d][64 key]

    int xrow = tid >> 4, xc4 = (tid & 15) * 4;
    const float* xp = xf + (size_t)(row0 + xrow) * 1024 + xc4;
    const short* wp0 = Wt + (size_t)(cg * 48 +  0 + c16) * 1024 + quad * 8;
    const short* wp1 = Wt + (size_t)(cg * 48 + 16 + c16) * 1024 + quad * 8;
    const short* wp2 = Wt + (size_t)(cg * 48 + 32 + c16) * 1024 + quad * 8;

    // ---- prologue: x(0) -> xs[0]; W(0) -> bA; x(64) -> xreg ----
    float4 xreg = *(const float4*)xp;
    {
        union { s4v v; unsigned u[2]; } pkv;
        pkv.u[0] = pk2(xreg.x, xreg.y);
        pkv.u[1] = pk2(xreg.z, xreg.w);
        *(s4v*)(&xs[0][xrow * 72 + xc4]) = pkv.v;
    }
    s8v bA[3][2], bB[3][2];
    #pragma unroll
    for (int ks = 0; ks < 2; ks++) {
        bA[0][ks] = *(const s8v*)(wp0 + ks * 32);
        bA[1][ks] = *(const s8v*)(wp1 + ks * 32);
        bA[2][ks] = *(const s8v*)(wp2 + ks * 32);
    }
    xreg = *(const float4*)(xp + 64);
    __syncthreads();

    f32x4 acc[3] = {};
    #pragma unroll
    for (int sp = 0; sp < 8; sp++) {
        const int ko = sp * 128;
        // ======== even step: consume xs[0] + bA(ko) ========
        {
            const int kn = ko + 64;                      // <= 960, valid
            #pragma unroll
            for (int ks = 0; ks < 2; ks++) {
                bB[0][ks] = *(const s8v*)(wp0 + kn + ks * 32);
                bB[1][ks] = *(const s8v*)(wp1 + kn + ks * 32);
                bB[2][ks] = *(const s8v*)(wp2 + kn + ks * 32);
            }
            {   // write x(kn) -> xs[1]
                union { s4v v; unsigned u[2]; } pkv;
                pkv.u[0] = pk2(xreg.x, xreg.y);
                pkv.u[1] = pk2(xreg.z, xreg.w);
                *(s4v*)(&xs[1][xrow * 72 + xc4]) = pkv.v;
            }
            const int kx = (kn + 64 < NEMBD) ? kn + 64 : 0;   // x(ko+128)
            xreg = *(const float4*)(xp + kx);
            #pragma unroll
            for (int ks = 0; ks < 2; ks++) {
                s8v a = *(const s8v*)(&xs[0][(rt * 16 + c16) * 72 + ks * 32 + quad * 8]);
                acc[0] = __builtin_amdgcn_mfma_f32_16x16x32_bf16(a, bA[0][ks], acc[0], 0, 0, 0);
                acc[1] = __builtin_amdgcn_mfma_f32_16x16x32_bf16(a, bA[1][ks], acc[1], 0, 0, 0);
                acc[2] = __builtin_amdgcn_mfma_f32_16x16x32_bf16(a, bA[2][ks], acc[2], 0, 0, 0);
            }
            __syncthreads();
        }
        // ======== odd step: consume xs[1] + bB(ko+64) ========
        {
            const int kn = (ko + 128 < NEMBD) ? ko + 128 : 0;   // W for next even
            #pragma unroll
            for (int ks = 0; ks < 2; ks++) {
                bA[0][ks] = *(const s8v*)(wp0 + kn + ks * 32);
                bA[1][ks] = *(const s8v*)(wp1 + kn + ks * 32);
                bA[2][ks] = *(const s8v*)(wp2 + kn + ks * 32);
            }
            {   // write x(ko+128) -> xs[0]
                union { s4v v; unsigned u[2]; } pkv;
                pkv.u[0] = pk2(xreg.x, xreg.y);
                pkv.u[1] = pk2(xreg.z, xreg.w);
                *(s4v*)(&xs[0][xrow * 72 + xc4]) = pkv.v;
            }
            const int kx = (ko + 192 < NEMBD) ? ko + 192 : 0;   // x(ko+192)
            xreg = *(const float4*)(xp + kx);
            #pragma unroll
            for (int ks = 0; ks < 2; ks++) {
                s8v a = *(const s8v*)(&xs[1][(rt * 16 + c16) * 72 + ks * 32 + quad * 8]);
                acc[0] = __builtin_amdgcn_mfma_f32_16x16x32_bf16(a, bB[0][ks], acc[0], 0, 0, 0);
                acc[1] = __builtin_amdgcn_mfma_f32_16x16x32_bf16(a, bB[1][ks], acc[1], 0, 0, 0);
                acc[2] = __builtin_amdgcn_mfma_f32_16x16x32_bf16(a, bB[2][ks], acc[2], 0, 0, 0);
            }
            __syncthreads();
        }
    }

    // ---- epilogue: identical to R19 ----
    #pragma unroll
    for (int j = 0; j < 3; j++) {
        int g = cg * 48 + j * 16 + c16;
        int mat = g >> 6, h = g & 63;
        if (mat < 2) {
            #pragma unroll
            for (int r = 0; r < 4; r++) {
                int row = row0 + rt * 16 + quad * 4 + r;
                QKV[(size_t)mat * BT * HS + (size_t)row * HS + h] = f2b_rne(acc[j][r]);
            }
        } else {
            int tg = row0 + rt * 16 + quad * 4;
            int b = tg >> 12, t = tg & 4095;
            size_t base = (((size_t)((b * 64 + (t >> 6)) * 64 + h)) << 6) + (t & 63);
            s4v pv;
            #pragma unroll
            for (int r = 0; r < 4; r++) pv[r] = f2b_rne(acc[j][r]);
            *(s4v*)(VpT + base) = pv;
        }
    }
}

// ---------------------------------------------------------------------------
// Kernel 3: causal flash attention — R0/R10 kernel VERBATIM (proven 41.6us).
// Seven structural variants (k-split+merge R11, K-prefetch R12, fused-pair
// R13/14, wide-block R15/16, q-split R17) established the law:
//   attn time = tile-iterations x ~1535 cyc*CU, invariant to per-tile MFMA
//   width, occupancy, and traffic.  This config (512 blocks x 8 waves,
//   16640 tiles, 64 VGPR, 36KB LDS) is the floor of this structure family.
// ---------------------------------------------------------------------------
__global__ __launch_bounds__(512, 4) void attn_kernel(
        const short* __restrict__ QKV, float* __restrict__ out) {
    __shared__ float smem[9216];   // 36 KB: P regions; epilogue overlays
    short* Ps = (short*)smem;

    int tid = threadIdx.x;
    int w = tid >> 6, l = tid & 63, quad = l >> 4, c16 = l & 15;
    int bi = blockIdx.x;
    int b  = (bi & 7) >> 1;                 // XCD-affine batch
    int r8 = bi >> 3;                       // 0..63
    int p  = bi & 1;
    int jt = (r8 < 32) ? (127 - (2 * r8 + p)) : (2 * (r8 - 32) + p);
    int q0 = jt * 32;

    const short* Qp  = QKV;
    const short* Kp  = QKV + (size_t)BT * HS;
    const short* VpT = QKV + 2 * (size_t)BT * HS;   // tiled
    size_t bT = (size_t)b * T_SEQ;

    s8v qf[2][2];
    #pragma unroll
    for (int qt = 0; qt < 2; qt++)
        #pragma unroll
        for (int h = 0; h < 2; h++)
            qf[qt][h] = *(const s8v*)(Qp + (bT + q0 + qt * 16 + c16) * HS + h * 32 + quad * 8);

    f32x4 o[2][4] = {};
    float lsum[2] = {0.f, 0.f};
    int nkt = (q0 >> 6) + 1;
    short* Pw[2] = { Ps + (w * 2) * 1152, Ps + (w * 2 + 1) * 1152 };
    const short* kbase = Kp + (bT + c16) * HS + quad * 8;
    const short* vbase = VpT + (((size_t)((b * 64) * 64 + c16)) << 6) + quad * 8;

    for (int kt = w; kt < nkt; kt += 8) {
        int kb = kt * 64;
        bool last = (kt == nkt - 1);

        // ---- phase 1: issue ALL K fragment loads (8 x b128, one wait) ----
        s8v kf[4][2];
        #pragma unroll
        for (int nt = 0; nt < 4; nt++) {
            const short* kr = kbase + (size_t)(kb + nt * 16) * HS;
            kf[nt][0] = *(const s8v*)kr;
            kf[nt][1] = *(const s8v*)(kr + 32);
        }
        // ---- phase 2: S^T = K * Q^T ----
        f32x4 st[2][4];
        #pragma unroll
        for (int nt = 0; nt < 4; nt++) {
            f32x4 z0 = {0.f, 0.f, 0.f, 0.f}, z1 = {0.f, 0.f, 0.f, 0.f};
            z0 = __builtin_amdgcn_mfma_f32_16x16x32_bf16(kf[nt][0], qf[0][0], z0, 0, 0, 0);
            z0 = __builtin_amdgcn_mfma_f32_16x16x32_bf16(kf[nt][1], qf[0][1], z0, 0, 0, 0);
            z1 = __builtin_amdgcn_mfma_f32_16x16x32_bf16(kf[nt][0], qf[1][0], z1, 0, 0, 0);
            z1 = __builtin_amdgcn_mfma_f32_16x16x32_bf16(kf[nt][1], qf[1][1], z1, 0, 0, 0);
            st[0][nt] = z0; st[1][nt] = z1;
        }
        // ---- phase 3: issue ALL V fragment loads (hidden by softmax) ----
        s8v vf[4][2];
        #pragma unroll
        for (int nt = 0; nt < 4; nt++) {
            const short* vr = vbase + (((size_t)(kt * 64 + nt * 16)) << 6);
            vf[nt][0] = *(const s8v*)vr;
            vf[nt][1] = *(const s8v*)(vr + 32);
        }
        // ---- phase 4: exp2, diag mask, lsum, pack P -> LDS ----
        #pragma unroll
        for (int qt = 0; qt < 2; qt++) {
            int qrow = q0 + qt * 16 + c16;
            #pragma unroll
            for (int nt = 0; nt < 4; nt++) {
                float pr[4];
                #pragma unroll
                for (int rr = 0; rr < 4; rr++) {
                    float v = st[qt][nt][rr];
                    if (last && (kb + nt * 16 + quad * 4 + rr > qrow)) v = -30000.f;
                    pr[rr] = __builtin_amdgcn_exp2f(v);
                    lsum[qt] += pr[rr];
                }
                union { s4v v; unsigned u[2]; } pkv;
                pkv.u[0] = pk2(pr[0], pr[1]); pkv.u[1] = pk2(pr[2], pr[3]);
                *(s4v*)(Pw[qt] + c16 * 72 + nt * 16 + quad * 4) = pkv.v;
            }
        }
        // ---- phase 5: P A-frags from LDS; phase 6: PV MFMAs ----
        s8v pa[2][2];
        #pragma unroll
        for (int qt = 0; qt < 2; qt++) {
            pa[qt][0] = *(const s8v*)(Pw[qt] + c16 * 72 + quad * 8);
            pa[qt][1] = *(const s8v*)(Pw[qt] + c16 * 72 + quad * 8 + 32);
        }
        #pragma unroll
        for (int nt = 0; nt < 4; nt++)
            #pragma unroll
            for (int qt = 0; qt < 2; qt++) {
                o[qt][nt] = __builtin_amdgcn_mfma_f32_16x16x32_bf16(pa[qt][0], vf[nt][0], o[qt][nt], 0, 0, 0);
                o[qt][nt] = __builtin_amdgcn_mfma_f32_16x16x32_bf16(pa[qt][1], vf[nt][1], o[qt][nt], 0, 0, 0);
            }
    }

    #pragma unroll
    for (int qt = 0; qt < 2; qt++) {
        lsum[qt] += __shfl_xor(lsum[qt], 16);
        lsum[qt] += __shfl_xor(lsum[qt], 32);
    }

    // two-phase per-lane merge (R5 fix)
    #pragma unroll
    for (int qt = 0; qt < 2; qt++) {
        __syncthreads();
        #pragma unroll
        for (int nt = 0; nt < 4; nt++)
            *(f32x4*)(smem + ((w * 4 + nt) * 64 + l) * 4) = o[qt][nt];
        if (l < 16) smem[8192 + w * 16 + l] = lsum[qt];
        __syncthreads();
        if (w < 4) {
            f32x4 os = {0.f, 0.f, 0.f, 0.f}, ls = {0.f, 0.f, 0.f, 0.f};
            #pragma unroll
            for (int s = 0; s < 8; s++) {
                os += *(const f32x4*)(smem + ((s * 4 + w) * 64 + l) * 4);
                ls += *(const f32x4*)(smem + 8192 + s * 16 + quad * 4);
            }
            #pragma unroll
            for (int rr = 0; rr < 4; rr++)
                out[(bT + q0 + qt * 16 + quad * 4 + rr) * HS + w * 16 + c16] = os[rr] / ls[rr];
        }
    }
}

// ---------------------------------------------------------------------------
extern "C" void kernel_launch(void* const* d_in, const int* in_sizes, int n_in,
                              void* d_out, int out_size, void* d_ws, size_t ws_size,
                              hipStream_t stream) {
    const float* x  = (const float*)d_in[0];
    const float* Wq = (const float*)d_in[1];
    const float* Wk = (const float*)d_in[2];
    const float* Wv = (const float*)d_in[3];
    float* out = (float*)d_out;

    short* QKV = (short*)d_ws;
    short* Wt  = QKV + (size_t)3 * BT * HS;

    wtrans_kernel<<<768, 256, 0, stream>>>(Wq, Wk, Wv, Wt);
    // R20: fp32-direct projection, W from L2 (reg-dbuf), 1 barrier/step.
    proj_kernel<<<BT / 32, 512, 0, stream>>>(x, Wt, QKV);
    attn_kernel<<<512, 512, 0, stream>>>(QKV, out);
}

// Round 11
// 151.381 us; speedup vs baseline: 1.1602x; 1.1602x over previous
//
#include <hip/hip_runtime.h>
#include <math.h>

#define T_SEQ 4096
#define NBATCH 4
#define NEMBD 1024
#define HS 64
#define BT (NBATCH * T_SEQ)   // 16384

typedef float f32x4 __attribute__((ext_vector_type(4)));
typedef short s8v  __attribute__((ext_vector_type(8)));   // 8 x bf16 bits
typedef short s4v  __attribute__((ext_vector_type(4)));   // 4 x bf16 bits

__device__ __forceinline__ short f2b_rne(float f) {
    union { float f; unsigned u; } v; v.f = f;
    unsigned r = v.u + 0x7fffu + ((v.u >> 16) & 1u);
    return (short)(r >> 16);
}
// pack 2 fp32 -> 2 bf16 (truncate) in one v_perm
__device__ __forceinline__ unsigned pk2(float lo, float hi) {
    return __builtin_amdgcn_perm(__float_as_uint(hi), __float_as_uint(lo), 0x07060302u);
}

// ---------------------------------------------------------------------------
// Kernel 1: W{q,k,v} [1024x64] fp32 -> Wt[192][1024] bf16 transposed.
// Softmax scale C^-0.5 * log2(e) folded into Wq.
// ---------------------------------------------------------------------------
__global__ __launch_bounds__(256) void wtrans_kernel(
        const float* __restrict__ Wq, const float* __restrict__ Wk,
        const float* __restrict__ Wv, short* __restrict__ Wt) {
    int e = blockIdx.x * 256 + threadIdx.x;
    int col = e & 63, k = (e >> 6) & 1023, mat = e >> 16;
    const float* W = (mat == 0) ? Wq : ((mat == 1) ? Wk : Wv);
    float scale = (mat == 0) ? 0.0450842298f : 1.0f;   // 2^-5 * log2(e)
    Wt[(size_t)(mat * 64 + col) * 1024 + k] = f2b_rne(W[k * 64 + col] * scale);
}

// ---------------------------------------------------------------------------
// Kernel 2: projections — R21 = R19's proven dataflow + LDS double-buffer.
// R20's lesson (VGPR_Count=40): the compiler DROPS register-held W prefetch
// and rematerializes loads at use -> serial L2 latency (57us).  R19's
// pattern survives compilation because the prefetched regs sink into LDS
// (memory ops aren't rematerialized).  R21 keeps that dataflow bit-for-bit
// and only double-buffers the LDS tiles (xs[2], wsh[2], 63KB) -> ONE
// barrier per 64-k step instead of two (16 barrier drains removed).
// Single-barrier safety: a wave re-writes buffer b only after passing a
// barrier that every reader of b has already passed.
// ---------------------------------------------------------------------------
__global__ __launch_bounds__(512) void proj_kernel(
        const float* __restrict__ xf, const short* __restrict__ Wt,
        short* __restrict__ QKV) {
    __shared__ short xs[2][32 * 72];
    __shared__ short wsh[2][192 * 72];
    int tid = threadIdx.x;
    int w = tid >> 6, l = tid & 63, quad = l >> 4, c16 = l & 15;
    int rt = w >> 2, cg = w & 3;
    int row0 = blockIdx.x * 32;
    short* VpT = QKV + 2 * (size_t)BT * HS;   // tiled [b][kt][64 d][64 key]

    int xrow = tid >> 4, xc4 = (tid & 15) * 4;

    s8v  wreg[3];
    float4 xreg;
    #pragma unroll
    for (int i = 0; i < 3; i++) {
        int c = tid + 512 * i;
        wreg[i] = *(const s8v*)(Wt + (size_t)(c >> 3) * 1024 + ((c & 7) * 8));
    }
    xreg = *(const float4*)(xf + (size_t)(row0 + xrow) * 1024 + xc4);

    f32x4 acc[3] = {};
    int buf = 0;
    for (int ko = 0; ko < NEMBD; ko += 64, buf ^= 1) {
        // ---- stage prefetched regs into LDS buffer `buf` ----
        #pragma unroll
        for (int i = 0; i < 3; i++) {
            int c = tid + 512 * i;
            *(s8v*)(&wsh[buf][(c >> 3) * 72 + ((c & 7) * 8)]) = wreg[i];
        }
        {
            union { s4v v; unsigned u[2]; } pkv;
            pkv.u[0] = pk2(xreg.x, xreg.y);
            pkv.u[1] = pk2(xreg.z, xreg.w);
            *(s4v*)(&xs[buf][xrow * 72 + xc4]) = pkv.v;
        }
        __syncthreads();
        // ---- prefetch next step's x/W into registers (sunk to LDS next) --
        {
            int kn = (ko + 64 < NEMBD) ? (ko + 64) : 0;
            #pragma unroll
            for (int i = 0; i < 3; i++) {
                int c = tid + 512 * i;
                wreg[i] = *(const s8v*)(Wt + (size_t)(c >> 3) * 1024 + kn + ((c & 7) * 8));
            }
            xreg = *(const float4*)(xf + (size_t)(row0 + xrow) * 1024 + kn + xc4);
        }
        // ---- MFMAs on buffer `buf` ----
        #pragma unroll
        for (int ks = 0; ks < 2; ks++) {
            s8v a = *(const s8v*)(&xs[buf][(rt * 16 + c16) * 72 + ks * 32 + quad * 8]);
            #pragma unroll
            for (int j = 0; j < 3; j++) {
                s8v b = *(const s8v*)(&wsh[buf][(cg * 48 + j * 16 + c16) * 72 + ks * 32 + quad * 8]);
                acc[j] = __builtin_amdgcn_mfma_f32_16x16x32_bf16(a, b, acc[j], 0, 0, 0);
            }
        }
        // no trailing barrier: next step writes the OTHER buffer
    }

    // ---- epilogue: identical to R19 ----
    #pragma unroll
    for (int j = 0; j < 3; j++) {
        int g = cg * 48 + j * 16 + c16;
        int mat = g >> 6, h = g & 63;
        if (mat < 2) {
            #pragma unroll
            for (int r = 0; r < 4; r++) {
                int row = row0 + rt * 16 + quad * 4 + r;
                QKV[(size_t)mat * BT * HS + (size_t)row * HS + h] = f2b_rne(acc[j][r]);
            }
        } else {
            int tg = row0 + rt * 16 + quad * 4;
            int b = tg >> 12, t = tg & 4095;
            size_t base = (((size_t)((b * 64 + (t >> 6)) * 64 + h)) << 6) + (t & 63);
            s4v pv;
            #pragma unroll
            for (int r = 0; r < 4; r++) pv[r] = f2b_rne(acc[j][r]);
            *(s4v*)(VpT + base) = pv;
        }
    }
}

// ---------------------------------------------------------------------------
// Kernel 3: causal flash attention — R0/R10 kernel VERBATIM (proven 41.6us).
// Seven structural variants (k-split+merge R11, K-prefetch R12, fused-pair
// R13/14, wide-block R15/16, q-split R17) established the law:
//   attn time = tile-iterations x ~1535 cyc*CU, invariant to per-tile MFMA
//   width, occupancy, and traffic.  This config (512 blocks x 8 waves,
//   16640 tiles, 64 VGPR, 36KB LDS) is the floor of this structure family.
// ---------------------------------------------------------------------------
__global__ __launch_bounds__(512, 4) void attn_kernel(
        const short* __restrict__ QKV, float* __restrict__ out) {
    __shared__ float smem[9216];   // 36 KB: P regions; epilogue overlays
    short* Ps = (short*)smem;

    int tid = threadIdx.x;
    int w = tid >> 6, l = tid & 63, quad = l >> 4, c16 = l & 15;
    int bi = blockIdx.x;
    int b  = (bi & 7) >> 1;                 // XCD-affine batch
    int r8 = bi >> 3;                       // 0..63
    int p  = bi & 1;
    int jt = (r8 < 32) ? (127 - (2 * r8 + p)) : (2 * (r8 - 32) + p);
    int q0 = jt * 32;

    const short* Qp  = QKV;
    const short* Kp  = QKV + (size_t)BT * HS;
    const short* VpT = QKV + 2 * (size_t)BT * HS;   // tiled
    size_t bT = (size_t)b * T_SEQ;

    s8v qf[2][2];
    #pragma unroll
    for (int qt = 0; qt < 2; qt++)
        #pragma unroll
        for (int h = 0; h < 2; h++)
            qf[qt][h] = *(const s8v*)(Qp + (bT + q0 + qt * 16 + c16) * HS + h * 32 + quad * 8);

    f32x4 o[2][4] = {};
    float lsum[2] = {0.f, 0.f};
    int nkt = (q0 >> 6) + 1;
    short* Pw[2] = { Ps + (w * 2) * 1152, Ps + (w * 2 + 1) * 1152 };
    const short* kbase = Kp + (bT + c16) * HS + quad * 8;
    const short* vbase = VpT + (((size_t)((b * 64) * 64 + c16)) << 6) + quad * 8;

    for (int kt = w; kt < nkt; kt += 8) {
        int kb = kt * 64;
        bool last = (kt == nkt - 1);

        // ---- phase 1: issue ALL K fragment loads (8 x b128, one wait) ----
        s8v kf[4][2];
        #pragma unroll
        for (int nt = 0; nt < 4; nt++) {
            const short* kr = kbase + (size_t)(kb + nt * 16) * HS;
            kf[nt][0] = *(const s8v*)kr;
            kf[nt][1] = *(const s8v*)(kr + 32);
        }
        // ---- phase 2: S^T = K * Q^T ----
        f32x4 st[2][4];
        #pragma unroll
        for (int nt = 0; nt < 4; nt++) {
            f32x4 z0 = {0.f, 0.f, 0.f, 0.f}, z1 = {0.f, 0.f, 0.f, 0.f};
            z0 = __builtin_amdgcn_mfma_f32_16x16x32_bf16(kf[nt][0], qf[0][0], z0, 0, 0, 0);
            z0 = __builtin_amdgcn_mfma_f32_16x16x32_bf16(kf[nt][1], qf[0][1], z0, 0, 0, 0);
            z1 = __builtin_amdgcn_mfma_f32_16x16x32_bf16(kf[nt][0], qf[1][0], z1, 0, 0, 0);
            z1 = __builtin_amdgcn_mfma_f32_16x16x32_bf16(kf[nt][1], qf[1][1], z1, 0, 0, 0);
            st[0][nt] = z0; st[1][nt] = z1;
        }
        // ---- phase 3: issue ALL V fragment loads (hidden by softmax) ----
        s8v vf[4][2];
        #pragma unroll
        for (int nt = 0; nt < 4; nt++) {
            const short* vr = vbase + (((size_t)(kt * 64 + nt * 16)) << 6);
            vf[nt][0] = *(const s8v*)vr;
            vf[nt][1] = *(const s8v*)(vr + 32);
        }
        // ---- phase 4: exp2, diag mask, lsum, pack P -> LDS ----
        #pragma unroll
        for (int qt = 0; qt < 2; qt++) {
            int qrow = q0 + qt * 16 + c16;
            #pragma unroll
            for (int nt = 0; nt < 4; nt++) {
                float pr[4];
                #pragma unroll
                for (int rr = 0; rr < 4; rr++) {
                    float v = st[qt][nt][rr];
                    if (last && (kb + nt * 16 + quad * 4 + rr > qrow)) v = -30000.f;
                    pr[rr] = __builtin_amdgcn_exp2f(v);
                    lsum[qt] += pr[rr];
                }
                union { s4v v; unsigned u[2]; } pkv;
                pkv.u[0] = pk2(pr[0], pr[1]); pkv.u[1] = pk2(pr[2], pr[3]);
                *(s4v*)(Pw[qt] + c16 * 72 + nt * 16 + quad * 4) = pkv.v;
            }
        }
        // ---- phase 5: P A-frags from LDS; phase 6: PV MFMAs ----
        s8v pa[2][2];
        #pragma unroll
        for (int qt = 0; qt < 2; qt++) {
            pa[qt][0] = *(const s8v*)(Pw[qt] + c16 * 72 + quad * 8);
            pa[qt][1] = *(const s8v*)(Pw[qt] + c16 * 72 + quad * 8 + 32);
        }
        #pragma unroll
        for (int nt = 0; nt < 4; nt++)
            #pragma unroll
            for (int qt = 0; qt < 2; qt++) {
                o[qt][nt] = __builtin_amdgcn_mfma_f32_16x16x32_bf16(pa[qt][0], vf[nt][0], o[qt][nt], 0, 0, 0);
                o[qt][nt] = __builtin_amdgcn_mfma_f32_16x16x32_bf16(pa[qt][1], vf[nt][1], o[qt][nt], 0, 0, 0);
            }
    }

    #pragma unroll
    for (int qt = 0; qt < 2; qt++) {
        lsum[qt] += __shfl_xor(lsum[qt], 16);
        lsum[qt] += __shfl_xor(lsum[qt], 32);
    }

    // two-phase per-lane merge (R5 fix)
    #pragma unroll
    for (int qt = 0; qt < 2; qt++) {
        __syncthreads();
        #pragma unroll
        for (int nt = 0; nt < 4; nt++)
            *(f32x4*)(smem + ((w * 4 + nt) * 64 + l) * 4) = o[qt][nt];
        if (l < 16) smem[8192 + w * 16 + l] = lsum[qt];
        __syncthreads();
        if (w < 4) {
            f32x4 os = {0.f, 0.f, 0.f, 0.f}, ls = {0.f, 0.f, 0.f, 0.f};
            #pragma unroll
            for (int s = 0; s < 8; s++) {
                os += *(const f32x4*)(smem + ((s * 4 + w) * 64 + l) * 4);
                ls += *(const f32x4*)(smem + 8192 + s * 16 + quad * 4);
            }
            #pragma unroll
            for (int rr = 0; rr < 4; rr++)
                out[(bT + q0 + qt * 16 + quad * 4 + rr) * HS + w * 16 + c16] = os[rr] / ls[rr];
        }
    }
}

// ---------------------------------------------------------------------------
extern "C" void kernel_launch(void* const* d_in, const int* in_sizes, int n_in,
                              void* d_out, int out_size, void* d_ws, size_t ws_size,
                              hipStream_t stream) {
    const float* x  = (const float*)d_in[0];
    const float* Wq = (const float*)d_in[1];
    const float* Wk = (const float*)d_in[2];
    const float* Wv = (const float*)d_in[3];
    float* out = (float*)d_out;

    short* QKV = (short*)d_ws;
    short* Wt  = QKV + (size_t)3 * BT * HS;

    wtrans_kernel<<<768, 256, 0, stream>>>(Wq, Wk, Wv, Wt);
    // R21: R19 dataflow + LDS double-buffer (1 barrier/step).
    proj_kernel<<<BT / 32, 512, 0, stream>>>(x, Wt, QKV);
    attn_kernel<<<512, 512, 0, stream>>>(QKV, out);
}